// Round 10
// baseline (276.118 us; speedup 1.0000x reference)
//
#include <hip/hip_runtime.h>
#include <hip/hip_bf16.h>

typedef unsigned short u16;
typedef __attribute__((ext_vector_type(8))) short bf16x8;
typedef __attribute__((ext_vector_type(4))) float f32x4;
typedef __attribute__((ext_vector_type(16))) float f32x16;
typedef __attribute__((ext_vector_type(4))) unsigned short u16x4;

#define B_  4
#define T_  1024
#define H_  1024
#define NH_ 16
#define HS_ 64
#define FF_ 4096
#define M_  (B_*T_)
#define QKV_S 3072

__device__ __forceinline__ u16 f2bf(float f){
  union { float f; unsigned u; } v; v.f = f;
  unsigned r = v.u + 0x7fffu + ((v.u >> 16) & 1u);
  return (u16)(r >> 16);
}
__device__ __forceinline__ float bf2f(u16 h){
  union { unsigned u; float f; } v; v.u = ((unsigned)h) << 16;
  return v.f;
}
__device__ __forceinline__ unsigned pack2bf(float a, float b){
  __hip_bfloat162 h = __float22bfloat162_rn(make_float2(a, b));
  union { __hip_bfloat162 h; unsigned u; } c; c.h = h;
  return c.u;
}

__device__ __forceinline__ void gload_lds16(const void* g, void* l){
  __builtin_amdgcn_global_load_lds(
      (const __attribute__((address_space(1))) unsigned int*)g,
      (__attribute__((address_space(3))) unsigned int*)l,
      16, 0, 0);
}

// swizzle for 32-row-span frag reads: period 32 rows (kills the 8-row bank cycle)
__device__ __forceinline__ int swz4(int r){ return ((r >> 1) & 3) ^ ((r >> 3) & 3); }

// ---------------- weight transpose + fp32->bf16 convert: Wt[n][k] = W[k][n]
__global__ __launch_bounds__(256) void transpose_cvt(const float* __restrict__ W,
                                                     u16* __restrict__ Wt, int K, int N)
{
  __shared__ u16 tile[64][68];
  const int k0 = blockIdx.y * 64, n0 = blockIdx.x * 64;
  const int tid = threadIdx.x;
  #pragma unroll
  for (int it = 0; it < 4; ++it){
    int ci = tid + it * 256;            // 1024 float4 chunks
    int kr = ci >> 4, nc = ci & 15;
    float4 f = *(const float4*)(W + (size_t)(k0 + kr) * N + n0 + nc * 4);
    tile[kr][nc*4+0] = f2bf(f.x);
    tile[kr][nc*4+1] = f2bf(f.y);
    tile[kr][nc*4+2] = f2bf(f.z);
    tile[kr][nc*4+3] = f2bf(f.w);
  }
  __syncthreads();
  #pragma unroll
  for (int it = 0; it < 4; ++it){
    int co = tid + it * 256;
    int nr = co >> 4, kc = co & 15;
    u16x4 o;
    o[0] = tile[kc*4+0][nr];
    o[1] = tile[kc*4+1][nr];
    o[2] = tile[kc*4+2][nr];
    o[3] = tile[kc*4+3][nr];
    *(u16x4*)(Wt + (size_t)(n0 + nr) * K + k0 + kc * 4) = o;
  }
}

// ---------------- per-head V transpose: vtg[bh][d][t] = v[b,t,h,d]
__global__ __launch_bounds__(256) void vtrans_k(const u16* __restrict__ qkv,
                                                u16* __restrict__ vtg)
{
  __shared__ u16 tile[64][72];
  const int bh = blockIdx.y, tt = blockIdx.x * 64;
  const int b = bh >> 4, h = bh & 15;
  const size_t src = (size_t)b * T_ * QKV_S + h * HS_ + 2048;
  const int tid = threadIdx.x;
  #pragma unroll
  for (int it = 0; it < 2; ++it){
    int ci = tid + it * 256;
    int r = ci >> 3, c = ci & 7;        // r = t-row, c = 16B chunk of d
    bf16x8 vvv = *(const bf16x8*)(qkv + src + (size_t)(tt + r) * QKV_S + c * 8);
    *(bf16x8*)&tile[r][c * 8] = vvv;
  }
  __syncthreads();
  #pragma unroll
  for (int it = 0; it < 2; ++it){
    int co = tid + it * 256;
    int d = co >> 3, c = co & 7;        // d = out row, c = t-chunk
    bf16x8 ov;
    #pragma unroll
    for (int j = 0; j < 8; ++j) ov[j] = (short)tile[c * 8 + j][d];
    *(bf16x8*)(vtg + (size_t)bh * HS_ * T_ + (size_t)d * T_ + tt + c * 8) = ov;
  }
}

// ---------------- concat 3 bias vectors (1024 each) -> 3072
__global__ void concat3_k(const float* __restrict__ a, const float* __restrict__ b,
                          const float* __restrict__ c, float* __restrict__ o){
  int i = blockIdx.x * 256 + threadIdx.x;
  if (i >= QKV_S) return;
  o[i] = (i < 1024) ? a[i] : (i < 2048) ? b[i - 1024] : c[i - 2048];
}

// ---------------- RoPE cos/sin table: tab[t][f] = {cos, sin}(t / 10000^(f/32))
__global__ void rope_table_k(float* __restrict__ tab){
  int i = blockIdx.x * blockDim.x + threadIdx.x;
  if (i >= T_ * 32) return;
  int t = i >> 5, f = i & 31;
  float inv = powf(10000.0f, -(float)f * (1.0f / 32.0f));
  float ang = (float)t * inv;
  tab[i*2+0] = cosf(ang);
  tab[i*2+1] = sinf(ang);
}

// ---------------- RoPE apply in-place on fused qkv
// q additionally scaled by (1/8)*log2(e): softmax runs in exp2 domain.
__global__ void rope_apply_k(u16* __restrict__ qkv, const float* __restrict__ tab){
  int i = blockIdx.x * blockDim.x + threadIdx.x;   // B*T*NH*32
  if (i >= B_*T_*NH_*32) return;
  int pr = i & 31;
  int nh = (i >> 5) & (NH_ - 1);
  int bt = i >> 9;                 // b*T + t
  int t  = bt & (T_ - 1);
  size_t idx = (size_t)bt * QKV_S + nh * HS_ + pr * 2;
  float c = tab[(t*32 + pr)*2], s = tab[(t*32 + pr)*2 + 1];
  const float qs = 0.125f * 1.44269504f;
  {
    float x0 = bf2f(qkv[idx]), x1 = bf2f(qkv[idx+1]);
    qkv[idx]   = f2bf((x0 * c - x1 * s) * qs);
    qkv[idx+1] = f2bf((x0 * s + x1 * c) * qs);
  }
  {
    float x0 = bf2f(qkv[idx+1024]), x1 = bf2f(qkv[idx+1025]);
    qkv[idx+1024] = f2bf(x0 * c - x1 * s);
    qkv[idx+1025] = f2bf(x0 * s + x1 * c);
  }
}

// ---------------- LayerNorm: fp32 in -> bf16 out, one row (1024) per block
__global__ __launch_bounds__(256) void ln_kernel(const float* __restrict__ x,
    const float* __restrict__ w, const float* __restrict__ bgain,
    u16* __restrict__ out)
{
  const int row = blockIdx.x;
  const int t = threadIdx.x;
  float4 vv = ((const float4*)(x + (size_t)row * H_))[t];
  float s  = vv.x + vv.y + vv.z + vv.w;
  float s2 = vv.x*vv.x + vv.y*vv.y + vv.z*vv.z + vv.w*vv.w;
  #pragma unroll
  for (int mm = 1; mm < 64; mm <<= 1){ s += __shfl_xor(s, mm); s2 += __shfl_xor(s2, mm); }
  __shared__ float red[8];
  int wid = t >> 6;
  if ((t & 63) == 0){ red[wid] = s; red[4 + wid] = s2; }
  __syncthreads();
  s  = red[0] + red[1] + red[2] + red[3];
  s2 = red[4] + red[5] + red[6] + red[7];
  float mu  = s * (1.0f / H_);
  float var = s2 * (1.0f / H_) - mu * mu;
  float rin = rsqrtf(var + 1e-5f);
  float4 wv = ((const float4*)w)[t];
  float4 bv = ((const float4*)bgain)[t];
  u16x4 ov;
  ov[0] = f2bf((vv.x - mu) * rin * wv.x + bv.x);
  ov[1] = f2bf((vv.y - mu) * rin * wv.y + bv.y);
  ov[2] = f2bf((vv.z - mu) * rin * wv.z + bv.z);
  ov[3] = f2bf((vv.w - mu) * rin * wv.w + bv.w);
  ((u16x4*)(out + (size_t)row * H_))[t] = ov;
}

// ---------------- GEMM: C[M,N] = A[M,K](bf16) @ Bt[N,K]^T(bf16) + bias (+epilogue)
// 32x32x16 MFMA, BM=128, row-major LDS with period-32 XOR swizzle (swz4):
// strided-8 lane batches hit 2-way max (free); staging stays coalesced.
// 512 thr = 8 waves (2m x 4n). BN=256/NI=2 or BN=128/NI=1.
// RING-slot ring, counted vmcnt, one barrier per K-step, reads-first.
// EPI 0: bf16. EPI 1: bf16 gelu(tanh/exp2). EPI 2: fp32 + residual.
template<int EPI, int BN, int NI, int RING>
__global__ __launch_bounds__(512, 4) void gemm_kernel(
    const u16* __restrict__ A, const u16* __restrict__ Bt,
    const float* __restrict__ bias, const float* __restrict__ res,
    void* __restrict__ Cout, int M, int N, int K)
{
  constexpr int LPT = (BN == 256) ? 3 : 2;   // gload_lds per thread per tile
  constexpr int DIST = RING - 1;
  __shared__ __attribute__((aligned(16))) u16 As[RING][128 * 32];
  __shared__ __attribute__((aligned(16))) u16 Bs[RING][BN * 32];
  const int tid  = threadIdx.x;
  const int lane = tid & 63;
  const int wid  = tid >> 6;           // 0..7
  const int wm = wid >> 2, wn = wid & 3;
  const int llo = lane & 31, lhi = lane >> 5;

  // XCD-aware bijective swizzle (all grids here have nwg % 8 == 0)
  const int gx  = gridDim.x;
  const int nwg = gx * gridDim.y;
  const int wg  = blockIdx.y * gx + blockIdx.x;
  const int nx  = nwg >> 3;
  const int swz = (wg & 7) * nx + (wg >> 3);
  const int m0 = (swz / gx) * 128, n0 = (swz % gx) * BN;

  // staging (row-major + swz4): thread -> row tid>>2, chunk (tid&3)^swz4(row)
  const int srow = tid >> 2;           // 0..127
  const int sdc  = tid & 3;
  const int scs  = sdc ^ swz4(srow);   // swz4(r+128)==swz4(r) -> Bsrc1 reuses it
  const u16* Asrc  = A  + (size_t)(m0 + srow) * K + scs * 8;
  const u16* Bsrc0 = Bt + (size_t)(n0 + srow) * K + scs * 8;
  const u16* Bsrc1 = Bsrc0 + (size_t)128 * K;   // rows +128 (BN=256 only)
  const int dA  = (srow * 4 + sdc) * 8;
  const int dB1 = dA + 128 * 32;

  // loop-invariant frag byte offsets
  int aoff[2][2], boff[NI][2];
  #pragma unroll
  for (int kh = 0; kh < 2; ++kh){
    #pragma unroll
    for (int mi = 0; mi < 2; ++mi){
      int r = wm*64 + mi*32 + llo;
      int c = (kh*2 + lhi) ^ swz4(r);
      aoff[mi][kh] = (r*4 + c) * 16;
    }
    #pragma unroll
    for (int ni = 0; ni < NI; ++ni){
      int r = wn*(NI*32) + ni*32 + llo;
      int c = (kh*2 + lhi) ^ swz4(r);
      boff[ni][kh] = (r*4 + c) * 16;
    }
  }

  f32x16 acc[2][NI] = {};
  const int NT = K >> 5;

  // prologue: stage tiles 0..DIST-1
  #pragma unroll
  for (int s = 0; s < DIST; ++s){
    gload_lds16(Asrc  + (s << 5), &As[s][dA]);
    gload_lds16(Bsrc0 + (s << 5), &Bs[s][dA]);
    if constexpr (BN == 256) gload_lds16(Bsrc1 + (s << 5), &Bs[s][dB1]);
  }

  int rs = 0, wsl = DIST;
  for (int t = 0; t < NT; ++t){
    int cnt = NT - 1 - t; if (cnt > DIST - 1) cnt = DIST - 1;
    if constexpr (RING == 5){
      if (cnt >= 3)      asm volatile("s_waitcnt vmcnt(6)" ::: "memory");
      else if (cnt == 2) asm volatile("s_waitcnt vmcnt(4)" ::: "memory");
      else if (cnt == 1) asm volatile("s_waitcnt vmcnt(2)" ::: "memory");
      else               asm volatile("s_waitcnt vmcnt(0)" ::: "memory");
    } else {   // RING == 3
      if (cnt >= 1){
        if constexpr (BN == 256) asm volatile("s_waitcnt vmcnt(3)" ::: "memory");
        else                     asm volatile("s_waitcnt vmcnt(2)" ::: "memory");
      } else {
        asm volatile("s_waitcnt vmcnt(0)" ::: "memory");
      }
    }
    __builtin_amdgcn_s_barrier();        // tile t visible; slot wsl free

    const char* Ab = (const char*)&As[rs][0];
    const char* Bb = (const char*)&Bs[rs][0];
    rs = (rs + 1 == RING) ? 0 : rs + 1;

    // frag reads FIRST (compiler emits fine-grained lgkmcnt before MFMAs)
    bf16x8 af[2][2], bfr[NI][2];
    #pragma unroll
    for (int kh = 0; kh < 2; ++kh){
      #pragma unroll
      for (int mi = 0; mi < 2; ++mi)
        af[mi][kh] = *(const bf16x8*)(Ab + aoff[mi][kh]);
      #pragma unroll
      for (int ni = 0; ni < NI; ++ni)
        bfr[ni][kh] = *(const bf16x8*)(Bb + boff[ni][kh]);
    }
    __builtin_amdgcn_sched_barrier(0);   // keep stage below the reads

    if (t + DIST < NT){                  // refill slot read at iter t-1
      int k0 = (t + DIST) << 5;
      gload_lds16(Asrc  + k0, &As[wsl][dA]);
      gload_lds16(Bsrc0 + k0, &Bs[wsl][dA]);
      if constexpr (BN == 256) gload_lds16(Bsrc1 + k0, &Bs[wsl][dB1]);
    }
    wsl = (wsl + 1 == RING) ? 0 : wsl + 1;

    #pragma unroll
    for (int kh = 0; kh < 2; ++kh)
      #pragma unroll
      for (int mi = 0; mi < 2; ++mi)
        #pragma unroll
        for (int ni = 0; ni < NI; ++ni)
          acc[mi][ni] = __builtin_amdgcn_mfma_f32_32x32x16_bf16(
              af[mi][kh], bfr[ni][kh], acc[mi][ni], 0, 0, 0);
  }

  // epilogue: C/D layout col=lane&31, row=(rg&3)+8*(rg>>2)+4*lhi
  #pragma unroll
  for (int mi = 0; mi < 2; ++mi){
    #pragma unroll
    for (int ni = 0; ni < NI; ++ni){
      int col = n0 + wn*(NI*32) + ni*32 + llo;
      float bv = bias[col];
      int rbase = m0 + wm*64 + mi*32 + 4*lhi;
      #pragma unroll
      for (int rg = 0; rg < 16; ++rg){
        int row = rbase + (rg & 3) + 8*(rg >> 2);
        float v = acc[mi][ni][rg] + bv;
        if (EPI == 1){
          float u = 0.7978845608f * v + 0.0356774081f * v * v * v;
          float e = exp2f(u * 2.8853900818f);   // e^(2u)
          v = v - v / (e + 1.0f);               // v*0.5*(1+tanh(u))
        }
        if (EPI == 2){
          ((float*)Cout)[(size_t)row * N + col] = v + res[(size_t)row * N + col];
        } else {
          ((u16*)Cout)[(size_t)row * N + col] = f2bf(v);
        }
      }
    }
  }
}

// ---------------- fused attention (swapped-operand form), 8 waves / 128 q-rows
__global__ __launch_bounds__(512, 4) void attn_kernel(
    const u16* __restrict__ qkv, const u16* __restrict__ vtg,
    u16* __restrict__ out)
{
  __shared__ u16 K_lds[3][64 * 64];
  __shared__ u16 VT_lds[3][64 * 64];
  __shared__ u16 P_lds[8][16 * 64];
  const int tid = threadIdx.x, lane = tid & 63, w = tid >> 6;   // w: 0..7
  const int lrow = lane & 15, lkg = lane >> 4;
  const int q0 = blockIdx.x * 128;
  const int bh = blockIdx.y, b = bh >> 4, h = bh & 15;
  const size_t baseq  = (size_t)b * T_ * QKV_S + h * HS_;
  const size_t basek  = baseq + 1024;
  const size_t basevt = (size_t)bh * HS_ * T_;
  const size_t baseo  = (size_t)b * T_ * H_ + h * HS_;
  const int qg = q0 + w * 16 + lrow;      // this lane's q row

  bf16x8 qa[2];
  {
    const u16* qp = qkv + baseq + (size_t)qg * QKV_S + lkg * 8;
    qa[0] = *(const bf16x8*)qp;
    qa[1] = *(const bf16x8*)(qp + 32);
  }

  const int r0 = tid >> 3, c0 = tid & 7, g0 = c0 ^ (r0 & 7);
  const u16* kap = qkv + basek + (size_t)r0 * QKV_S + g0 * 8;
  const u16* vap = vtg + basevt + (size_t)r0 * T_ + g0 * 8;
  const int kd = tid * 8;

  f32x4 o[4] = {};
  float mrun = -1e30f, lrun = 0.f;

  #pragma unroll
  for (int s = 0; s < 2; ++s){
    gload_lds16(kap + (size_t)s * 64 * QKV_S, &K_lds[s][kd]);
    gload_lds16(vap + s * 64,                 &VT_lds[s][kd]);
  }

  int rs = 0, wsl = 2;
  for (int t = 0; t < 16; ++t){
    const int kt = t << 6;
    if (t < 15) asm volatile("s_waitcnt vmcnt(2)" ::: "memory");
    else        asm volatile("s_waitcnt vmcnt(0)" ::: "memory");
    __builtin_amdgcn_s_barrier();
    __builtin_amdgcn_sched_barrier(0);

    if (t + 2 < 16){
      gload_lds16(kap + (size_t)(t + 2) * 64 * QKV_S, &K_lds[wsl][kd]);
      gload_lds16(vap + (t + 2) * 64,                 &VT_lds[wsl][kd]);
    }
    wsl = (wsl + 1 == 3) ? 0 : wsl + 1;

    const u16* Kc  = K_lds[rs];
    const u16* VTc = VT_lds[rs];
    rs = (rs + 1 == 3) ? 0 : rs + 1;

    f32x4 s[4];
    __builtin_amdgcn_s_setprio(1);
    #pragma unroll
    for (int mi = 0; mi < 4; ++mi){
      f32x4 c = {};
      #pragma unroll
      for (int ss = 0; ss < 2; ++ss){
        int r = mi * 16 + lrow;
        int off = r * 128 + (((ss * 4 + lkg) ^ (r & 7)) * 16);
        bf16x8 kb = *(const bf16x8*)((const char*)Kc + off);
        c = __builtin_amdgcn_mfma_f32_16x16x32_bf16(kb, qa[ss], c, 0, 0, 0);
      }
      s[mi] = c;
    }
    __builtin_amdgcn_s_setprio(0);

    float mt = fmaxf(fmaxf(fmaxf(s[0][0], s[0][1]), fmaxf(s[0][2], s[0][3])),
                     fmaxf(fmaxf(s[1][0], s[1][1]), fmaxf(s[1][2], s[1][3])));
    mt = fmaxf(mt, fmaxf(fmaxf(fmaxf(s[2][0], s[2][1]), fmaxf(s[2][2], s[2][3])),
                         fmaxf(fmaxf(s[3][0], s[3][1]), fmaxf(s[3][2], s[3][3]))));
    mt = fmaxf(mt, __shfl_xor(mt, 16));
    mt = fmaxf(mt, __shfl_xor(mt, 32));
    if (!__all(mt <= mrun + 8.f)){       // defer-max
      float mnew = fmaxf(mrun, mt);
      float fsc = exp2f(mrun - mnew);
      lrun *= fsc;
      #pragma unroll
      for (int nf = 0; nf < 4; ++nf){
        #pragma unroll
        for (int r = 0; r < 4; ++r) o[nf][r] *= fsc;
      }
      mrun = mnew;
    }

    float p[16];
    float ls = 0.f;
    #pragma unroll
    for (int mi = 0; mi < 4; ++mi){
      #pragma unroll
      for (int r = 0; r < 4; ++r){
        int key = kt + mi * 16 + lkg * 4 + r;
        float pv = exp2f(s[mi][r] - mrun);
        ls += pv;                          // denominator over ALL keys
        p[mi * 4 + r] = (key <= qg) ? pv : 0.f;
      }
    }
    ls += __shfl_xor(ls, 16);
    ls += __shfl_xor(ls, 32);
    lrun += ls;

    if (kt <= q0 + w * 16 + 15){
      char* pbase = (char*)&P_lds[w][0];
      const int rx = (lrow & 7) << 4;
      #pragma unroll
      for (int mi = 0; mi < 4; ++mi){
        uint2 pk;
        pk.x = pack2bf(p[mi*4+0], p[mi*4+1]);
        pk.y = pack2bf(p[mi*4+2], p[mi*4+3]);
        *(uint2*)(pbase + (lrow * 128 + ((mi * 32 + lkg * 8) ^ rx))) = pk;
      }
      __builtin_amdgcn_s_setprio(1);
      #pragma unroll
      for (int ss = 0; ss < 2; ++ss){
        bf16x8 pb = *(const bf16x8*)(pbase + (lrow * 128 + ((ss * 64 + lkg * 16) ^ rx)));
        #pragma unroll
        for (int nfd = 0; nfd < 4; ++nfd){
          int d = nfd * 16 + lrow;
          int off = d * 128 + (((ss * 4 + lkg) ^ (d & 7)) * 16);
          bf16x8 vb = *(const bf16x8*)((const char*)VTc + off);
          o[nfd] = __builtin_amdgcn_mfma_f32_16x16x32_bf16(vb, pb, o[nfd], 0, 0, 0);
        }
      }
      __builtin_amdgcn_s_setprio(0);
    }
  }

  float rl = 1.0f / lrun;
  #pragma unroll
  for (int nfd = 0; nfd < 4; ++nfd){
    uint2 ov;
    ov.x = pack2bf(o[nfd][0] * rl, o[nfd][1] * rl);
    ov.y = pack2bf(o[nfd][2] * rl, o[nfd][3] * rl);
    *(uint2*)(out + baseo + (size_t)qg * H_ + nfd * 16 + lkg * 4) = ov;
  }
}

extern "C" void kernel_launch(void* const* d_in, const int* in_sizes, int n_in,
                              void* d_out, int out_size, void* d_ws, size_t ws_size,
                              hipStream_t stream)
{
  (void)in_sizes; (void)n_in; (void)out_size; (void)ws_size;
  const float* x    = (const float*)d_in[0];
  const float* Wq   = (const float*)d_in[1];
  const float* bq   = (const float*)d_in[2];
  const float* Wk   = (const float*)d_in[3];
  const float* bk   = (const float*)d_in[4];
  const float* Wv   = (const float*)d_in[5];
  const float* bv   = (const float*)d_in[6];
  const float* Wo   = (const float*)d_in[7];
  const float* bo   = (const float*)d_in[8];
  const float* ln1w = (const float*)d_in[9];
  const float* ln1b = (const float*)d_in[10];
  const float* ln2w = (const float*)d_in[11];
  const float* ln2b = (const float*)d_in[12];
  const float* Wfc  = (const float*)d_in[13];
  const float* bfc  = (const float*)d_in[14];
  const float* Wpr  = (const float*)d_in[15];
  const float* bpr  = (const float*)d_in[16];

  char* ws = (char*)d_ws;
  u16*  WqkvT = (u16*)(ws + ((size_t) 0 << 20));   //  6MB [3072][1024]
  u16*  WoT   = (u16*)(ws + ((size_t) 6 << 20));   //  2MB
  u16*  WfcT  = (u16*)(ws + ((size_t) 8 << 20));   //  8MB [FF][H]
  u16*  WprT  = (u16*)(ws + ((size_t)16 << 20));   //  8MB [H][FF]
  u16*  h1    = (u16*)(ws + ((size_t)24 << 20));   //  8MB; reused as attnout
  u16*  qkvb  = (u16*)(ws + ((size_t)32 << 20));   // 24MB [M][3072]; dead after attn
  float* x1   = (float*)(ws + ((size_t)32 << 20)); // 16MB (reuses qkvb region)
  u16*  h2    = (u16*)(ws + ((size_t)48 << 20));   //  8MB (reuses qkvb region)
  float* bqkv = (float*)(ws + ((size_t)56 << 20)); // 12KB (dead before mb written)
  float* rtab = (float*)(ws + ((size_t)56 << 20) + (64 << 10)); // 256KB (dead before mb)
  u16*  vtg   = (u16*)(ws + ((size_t)57 << 20));   //  8MB [64 bh][64 d][1024 t] (dead before mb)
  u16*  mb    = (u16*)(ws + ((size_t)56 << 20));   // 32MB (overwrites bqkv/rtab/vtg)
  u16*  attnout = h1;

  dim3 blk(256);
  dim3 gblk(512);

  // weights: transpose + bf16 (QKV concatenated along output dim)
  transpose_cvt<<<dim3(H_/64,  H_/64),  blk, 0, stream>>>(Wq,  WqkvT,                 H_,  H_);
  transpose_cvt<<<dim3(H_/64,  H_/64),  blk, 0, stream>>>(Wk,  WqkvT + (size_t)1024*1024, H_,  H_);
  transpose_cvt<<<dim3(H_/64,  H_/64),  blk, 0, stream>>>(Wv,  WqkvT + (size_t)2048*1024, H_,  H_);
  transpose_cvt<<<dim3(H_/64,  H_/64),  blk, 0, stream>>>(Wo,  WoT,  H_,  H_);
  transpose_cvt<<<dim3(FF_/64, H_/64),  blk, 0, stream>>>(Wfc, WfcT, H_,  FF_);
  transpose_cvt<<<dim3(H_/64,  FF_/64), blk, 0, stream>>>(Wpr, WprT, FF_, H_);
  concat3_k<<<dim3((QKV_S+255)/256), blk, 0, stream>>>(bq, bk, bv, bqkv);
  rope_table_k<<<dim3((T_*32)/256), blk, 0, stream>>>(rtab);

  // LN1
  ln_kernel<<<dim3(M_), blk, 0, stream>>>(x, ln1w, ln1b, h1);
  // fused QKV projection: [M,3072] — BN=256 RING=3, grid 12x32=384
  gemm_kernel<0,256,2,3><<<dim3(QKV_S/256, M_/128), gblk, 0, stream>>>(h1, WqkvT, bqkv, nullptr, qkvb, M_, QKV_S, H_);
  // RoPE on q,k slices (exp2 domain); per-head V transpose
  rope_apply_k<<<dim3((B_*T_*NH_*32)/256), blk, 0, stream>>>(qkvb, rtab);
  vtrans_k<<<dim3(T_/64, B_*NH_), blk, 0, stream>>>(qkvb, vtg);
  // attention — 8 waves, 128 q-rows/block
  attn_kernel<<<dim3(T_/128, B_*NH_), dim3(512), 0, stream>>>(qkvb, vtg, attnout);
  // out projection + residual -> x1 (fp32) — BN=128 RING=5 (deep prefetch, 1 blk/CU)
  gemm_kernel<2,128,1,5><<<dim3(H_/128, M_/128), gblk, 0, stream>>>(attnout, WoT, bo, x, x1, M_, H_, H_);
  // LN2
  ln_kernel<<<dim3(M_), blk, 0, stream>>>(x1, ln2w, ln2b, h2);
  // MLP — Wfc BN=256 RING=3 grid 16x32=512; Wpr BN=128 RING=5 grid 256
  gemm_kernel<1,256,2,3><<<dim3(FF_/256, M_/128), gblk, 0, stream>>>(h2, WfcT, bfc, nullptr, mb, M_, FF_, H_);
  gemm_kernel<2,128,1,5><<<dim3(H_/128, M_/128), gblk, 0, stream>>>(mb, WprT, bpr, x1, (float*)d_out, M_, H_, FF_);
}

// Round 11
// 254.018 us; speedup vs baseline: 1.0870x; 1.0870x over previous
//
#include <hip/hip_runtime.h>
#include <hip/hip_bf16.h>

typedef unsigned short u16;
typedef __attribute__((ext_vector_type(8))) short bf16x8;
typedef __attribute__((ext_vector_type(4))) float f32x4;
typedef __attribute__((ext_vector_type(4))) unsigned short u16x4;

#define B_  4
#define T_  1024
#define H_  1024
#define NH_ 16
#define HS_ 64
#define FF_ 4096
#define M_  (B_*T_)
#define QKV_S 3072

__device__ __forceinline__ u16 f2bf(float f){
  union { float f; unsigned u; } v; v.f = f;
  unsigned r = v.u + 0x7fffu + ((v.u >> 16) & 1u);
  return (u16)(r >> 16);
}
__device__ __forceinline__ float bf2f(u16 h){
  union { unsigned u; float f; } v; v.u = ((unsigned)h) << 16;
  return v.f;
}
__device__ __forceinline__ unsigned pack2bf(float a, float b){
  __hip_bfloat162 h = __float22bfloat162_rn(make_float2(a, b));
  union { __hip_bfloat162 h; unsigned u; } c; c.h = h;
  return c.u;
}

__device__ __forceinline__ void gload_lds16(const void* g, void* l){
  __builtin_amdgcn_global_load_lds(
      (const __attribute__((address_space(1))) unsigned int*)g,
      (__attribute__((address_space(3))) unsigned int*)l,
      16, 0, 0);
}

// ---------------- 64x64 transpose tile body (fp32 -> bf16)
__device__ __forceinline__ void trans_tile(const float* __restrict__ W,
                                           u16* __restrict__ Wt, int K, int N,
                                           int k0, int n0, int tid)
{
  __shared__ u16 tile[64][68];
  #pragma unroll
  for (int it = 0; it < 4; ++it){
    int ci = tid + it * 256;
    int kr = ci >> 4, nc = ci & 15;
    float4 f = *(const float4*)(W + (size_t)(k0 + kr) * N + n0 + nc * 4);
    tile[kr][nc*4+0] = f2bf(f.x);
    tile[kr][nc*4+1] = f2bf(f.y);
    tile[kr][nc*4+2] = f2bf(f.z);
    tile[kr][nc*4+3] = f2bf(f.w);
  }
  __syncthreads();
  #pragma unroll
  for (int it = 0; it < 4; ++it){
    int co = tid + it * 256;
    int nr = co >> 4, kc = co & 15;
    u16x4 o;
    o[0] = tile[kc*4+0][nr];
    o[1] = tile[kc*4+1][nr];
    o[2] = tile[kc*4+2][nr];
    o[3] = tile[kc*4+3][nr];
    *(u16x4*)(Wt + (size_t)(n0 + nr) * K + k0 + kc * 4) = o;
  }
}

// ---------------- fused 4x HxH weight transpose (Wq,Wk,Wv -> WqkvT; Wo -> WoT)
__global__ __launch_bounds__(256) void trans_qkvo_k(
    const float* __restrict__ Wq, const float* __restrict__ Wk,
    const float* __restrict__ Wv, const float* __restrict__ Wo,
    u16* __restrict__ WqkvT, u16* __restrict__ WoT)
{
  const int z = blockIdx.z;
  const float* src = (z == 0) ? Wq : (z == 1) ? Wk : (z == 2) ? Wv : Wo;
  u16* dst = (z == 3) ? WoT : (WqkvT + (size_t)z * 1024 * 1024);
  trans_tile(src, dst, H_, H_, blockIdx.y * 64, blockIdx.x * 64, threadIdx.x);
}

// ---------------- generic transpose (Wfc, Wpr)
__global__ __launch_bounds__(256) void transpose_cvt(const float* __restrict__ W,
                                                     u16* __restrict__ Wt, int K, int N)
{
  trans_tile(W, Wt, K, N, blockIdx.y * 64, blockIdx.x * 64, threadIdx.x);
}

// ---------------- per-head V transpose: vtg[bh][d][t] = v[b,t,h,d]
__global__ __launch_bounds__(256) void vtrans_k(const u16* __restrict__ qkv,
                                                u16* __restrict__ vtg)
{
  __shared__ u16 tile[64][72];
  const int bh = blockIdx.y, tt = blockIdx.x * 64;
  const int b = bh >> 4, h = bh & 15;
  const size_t src = (size_t)b * T_ * QKV_S + h * HS_ + 2048;
  const int tid = threadIdx.x;
  #pragma unroll
  for (int it = 0; it < 2; ++it){
    int ci = tid + it * 256;
    int r = ci >> 3, c = ci & 7;
    bf16x8 vvv = *(const bf16x8*)(qkv + src + (size_t)(tt + r) * QKV_S + c * 8);
    *(bf16x8*)&tile[r][c * 8] = vvv;
  }
  __syncthreads();
  #pragma unroll
  for (int it = 0; it < 2; ++it){
    int co = tid + it * 256;
    int d = co >> 3, c = co & 7;
    bf16x8 ov;
    #pragma unroll
    for (int j = 0; j < 8; ++j) ov[j] = (short)tile[c * 8 + j][d];
    *(bf16x8*)(vtg + (size_t)bh * HS_ * T_ + (size_t)d * T_ + tt + c * 8) = ov;
  }
}

// ---------------- small prep: bias concat (3072) + rope cos/sin table (32768)
__global__ void prep_small_k(const float* __restrict__ a, const float* __restrict__ b,
                             const float* __restrict__ c, float* __restrict__ o,
                             float* __restrict__ tab){
  int i = blockIdx.x * 256 + threadIdx.x;
  if (i < QKV_S){
    o[i] = (i < 1024) ? a[i] : (i < 2048) ? b[i - 1024] : c[i - 2048];
  } else {
    int j = i - QKV_S;
    if (j < T_ * 32){
      int t = j >> 5, f = j & 31;
      float inv = powf(10000.0f, -(float)f * (1.0f / 32.0f));
      float ang = (float)t * inv;
      tab[j*2+0] = cosf(ang);
      tab[j*2+1] = sinf(ang);
    }
  }
}

// ---------------- RoPE apply in-place on fused qkv
// q additionally scaled by (1/8)*log2(e): softmax runs in exp2 domain.
__global__ void rope_apply_k(u16* __restrict__ qkv, const float* __restrict__ tab){
  int i = blockIdx.x * blockDim.x + threadIdx.x;   // B*T*NH*32
  if (i >= B_*T_*NH_*32) return;
  int pr = i & 31;
  int nh = (i >> 5) & (NH_ - 1);
  int bt = i >> 9;
  int t  = bt & (T_ - 1);
  size_t idx = (size_t)bt * QKV_S + nh * HS_ + pr * 2;
  float c = tab[(t*32 + pr)*2], s = tab[(t*32 + pr)*2 + 1];
  const float qs = 0.125f * 1.44269504f;
  {
    float x0 = bf2f(qkv[idx]), x1 = bf2f(qkv[idx+1]);
    qkv[idx]   = f2bf((x0 * c - x1 * s) * qs);
    qkv[idx+1] = f2bf((x0 * s + x1 * c) * qs);
  }
  {
    float x0 = bf2f(qkv[idx+1024]), x1 = bf2f(qkv[idx+1025]);
    qkv[idx+1024] = f2bf(x0 * c - x1 * s);
    qkv[idx+1025] = f2bf(x0 * s + x1 * c);
  }
}

// ---------------- LayerNorm: fp32 in -> bf16 out, one row (1024) per block
__global__ __launch_bounds__(256) void ln_kernel(const float* __restrict__ x,
    const float* __restrict__ w, const float* __restrict__ bgain,
    u16* __restrict__ out)
{
  const int row = blockIdx.x;
  const int t = threadIdx.x;
  float4 vv = ((const float4*)(x + (size_t)row * H_))[t];
  float s  = vv.x + vv.y + vv.z + vv.w;
  float s2 = vv.x*vv.x + vv.y*vv.y + vv.z*vv.z + vv.w*vv.w;
  #pragma unroll
  for (int mm = 1; mm < 64; mm <<= 1){ s += __shfl_xor(s, mm); s2 += __shfl_xor(s2, mm); }
  __shared__ float red[8];
  int wid = t >> 6;
  if ((t & 63) == 0){ red[wid] = s; red[4 + wid] = s2; }
  __syncthreads();
  s  = red[0] + red[1] + red[2] + red[3];
  s2 = red[4] + red[5] + red[6] + red[7];
  float mu  = s * (1.0f / H_);
  float var = s2 * (1.0f / H_) - mu * mu;
  float rin = rsqrtf(var + 1e-5f);
  float4 wv = ((const float4*)w)[t];
  float4 bv = ((const float4*)bgain)[t];
  u16x4 ov;
  ov[0] = f2bf((vv.x - mu) * rin * wv.x + bv.x);
  ov[1] = f2bf((vv.y - mu) * rin * wv.y + bv.y);
  ov[2] = f2bf((vv.z - mu) * rin * wv.z + bv.z);
  ov[3] = f2bf((vv.w - mu) * rin * wv.w + bv.w);
  ((u16x4*)(out + (size_t)row * H_))[t] = ov;
}

// ---------------- GEMM: C[M,N] = A[M,K](bf16) @ Bt[N,K]^T(bf16) + bias (+epilogue)
// Round-7 structure (verified 263us total, 0 bank conflicts): 16x16x32 MFMA,
// 512 thr = 8 waves (2m x 4n), wave tile 64x32, BM=BN=128, row-major LDS with
// (r>>1)&3 XOR swizzle, RING ring, counted vmcnt, one barrier/K-step,
// reads-first. Frag offsets hoisted. EPI 0: bf16. EPI 1: bf16 gelu(tanh/exp2).
// EPI 2: fp32 + residual.
template<int EPI, int RING>
__global__ __launch_bounds__(512) void gemm_kernel(
    const u16* __restrict__ A, const u16* __restrict__ Bt,
    const float* __restrict__ bias, const float* __restrict__ res,
    void* __restrict__ Cout, int M, int N, int K)
{
  __shared__ __attribute__((aligned(16))) u16 As[RING][128 * 32];
  __shared__ __attribute__((aligned(16))) u16 Bs[RING][128 * 32];
  const int tid  = threadIdx.x;
  const int lane = tid & 63;
  const int wid  = tid >> 6;           // 0..7
  const int wm = wid >> 2, wn = wid & 3;
  const int lrow = lane & 15, lkg = lane >> 4;

  // XCD-aware bijective swizzle (all grids here have nwg % 8 == 0)
  const int gx  = gridDim.x;
  const int nwg = gx * gridDim.y;
  const int wg  = blockIdx.y * gx + blockIdx.x;
  const int nx  = nwg >> 3;
  const int swz = (wg & 7) * nx + (wg >> 3);
  const int m0 = (swz / gx) * 128, n0 = (swz % gx) * 128;

  const int srow = tid >> 2;   // 0..127
  const int sdc  = tid & 3;
  const int scs  = sdc ^ ((srow >> 1) & 3);

  const u16* Arow = A  + (size_t)(m0 + srow) * K + scs * 8;
  const u16* Brow = Bt + (size_t)(n0 + srow) * K + scs * 8;
  const int dd = (srow * 4 + sdc) * 8;

  // loop-invariant frag byte offsets
  int aoff[4], boff[2];
  #pragma unroll
  for (int mi = 0; mi < 4; ++mi){
    int r = wm*64 + mi*16 + lrow;
    aoff[mi] = (r*4 + (lkg ^ ((r >> 1) & 3))) * 16;
  }
  #pragma unroll
  for (int ni = 0; ni < 2; ++ni){
    int r = wn*32 + ni*16 + lrow;
    boff[ni] = (r*4 + (lkg ^ ((r >> 1) & 3))) * 16;
  }

  f32x4 acc[4][2] = {};
  const int NT = K >> 5;
  constexpr int DIST = RING - 1;

  // prologue: stage tiles 0..DIST-1
  #pragma unroll
  for (int s = 0; s < DIST; ++s){
    gload_lds16(Arow + (s << 5), &As[s][dd]);
    gload_lds16(Brow + (s << 5), &Bs[s][dd]);
  }

  int rs = 0, wsl = DIST;
  for (int t = 0; t < NT; ++t){
    int cnt = NT - 1 - t; if (cnt > DIST - 1) cnt = DIST - 1;
    if (cnt >= 4)      asm volatile("s_waitcnt vmcnt(8)" ::: "memory");
    else if (cnt == 3) asm volatile("s_waitcnt vmcnt(6)" ::: "memory");
    else if (cnt == 2) asm volatile("s_waitcnt vmcnt(4)" ::: "memory");
    else if (cnt == 1) asm volatile("s_waitcnt vmcnt(2)" ::: "memory");
    else               asm volatile("s_waitcnt vmcnt(0)" ::: "memory");
    __builtin_amdgcn_s_barrier();        // all waves' tile-t loads landed

    const char* Ab = (const char*)&As[rs][0];
    const char* Bb = (const char*)&Bs[rs][0];
    rs = (rs + 1 == RING) ? 0 : rs + 1;

    // frag reads FIRST (critical path) — compiler emits fine-grained lgkmcnt
    bf16x8 af[4], bfr[2];
    #pragma unroll
    for (int mi = 0; mi < 4; ++mi)
      af[mi] = *(const bf16x8*)(Ab + aoff[mi]);
    #pragma unroll
    for (int ni = 0; ni < 2; ++ni)
      bfr[ni] = *(const bf16x8*)(Bb + boff[ni]);
    __builtin_amdgcn_sched_barrier(0);   // keep stage below the reads

    if (t + DIST < NT){                  // refill slot read at iter t-1
      int k0 = (t + DIST) << 5;
      gload_lds16(Arow + k0, &As[wsl][dd]);
      gload_lds16(Brow + k0, &Bs[wsl][dd]);
    }
    wsl = (wsl + 1 == RING) ? 0 : wsl + 1;

    #pragma unroll
    for (int mi = 0; mi < 4; ++mi)
      #pragma unroll
      for (int ni = 0; ni < 2; ++ni)
        acc[mi][ni] = __builtin_amdgcn_mfma_f32_16x16x32_bf16(af[mi], bfr[ni], acc[mi][ni], 0, 0, 0);
  }

  #pragma unroll
  for (int mi = 0; mi < 4; ++mi){
    #pragma unroll
    for (int ni = 0; ni < 2; ++ni){
      int col = n0 + wn*32 + ni*16 + lrow;
      float bv = bias[col];
      #pragma unroll
      for (int r = 0; r < 4; ++r){
        int row = m0 + wm*64 + mi*16 + lkg*4 + r;
        float v = acc[mi][ni][r] + bv;
        if (EPI == 1){
          float u = 0.7978845608f * v + 0.0356774081f * v * v * v;
          float e = exp2f(u * 2.8853900818f);   // e^(2u)
          v = v - v / (e + 1.0f);               // v*0.5*(1+tanh(u))
        }
        if (EPI == 2){
          ((float*)Cout)[(size_t)row * N + col] = v + res[(size_t)row * N + col];
        } else {
          ((u16*)Cout)[(size_t)row * N + col] = f2bf(v);
        }
      }
    }
  }
}

// ---------------- fused attention (swapped-operand form), 8 waves / 128 q-rows
// S^T = mfma(K, Q): lane owns one q-row and 16 keys in regs; exp2-domain
// softmax with defer-max (THR=8). O^T = mfma(V^T, P).
// 3-slot LDS ring, counted vmcnt, one barrier per tile.
// Full-row softmax denominator; causal mask applied to P only (matches ref).
__global__ __launch_bounds__(512, 4) void attn_kernel(
    const u16* __restrict__ qkv, const u16* __restrict__ vtg,
    u16* __restrict__ out)
{
  __shared__ u16 K_lds[3][64 * 64];
  __shared__ u16 VT_lds[3][64 * 64];
  __shared__ u16 P_lds[8][16 * 64];
  const int tid = threadIdx.x, lane = tid & 63, w = tid >> 6;   // w: 0..7
  const int lrow = lane & 15, lkg = lane >> 4;
  const int q0 = blockIdx.x * 128;
  const int bh = blockIdx.y, b = bh >> 4, h = bh & 15;
  const size_t baseq  = (size_t)b * T_ * QKV_S + h * HS_;
  const size_t basek  = baseq + 1024;
  const size_t basevt = (size_t)bh * HS_ * T_;
  const size_t baseo  = (size_t)b * T_ * H_ + h * HS_;
  const int qg = q0 + w * 16 + lrow;      // this lane's q row

  bf16x8 qa[2];
  {
    const u16* qp = qkv + baseq + (size_t)qg * QKV_S + lkg * 8;
    qa[0] = *(const bf16x8*)qp;
    qa[1] = *(const bf16x8*)(qp + 32);
  }

  const int r0 = tid >> 3, c0 = tid & 7, g0 = c0 ^ (r0 & 7);
  const u16* kap = qkv + basek + (size_t)r0 * QKV_S + g0 * 8;
  const u16* vap = vtg + basevt + (size_t)r0 * T_ + g0 * 8;
  const int kd = tid * 8;

  f32x4 o[4] = {};
  float mrun = -1e30f, lrun = 0.f;

  #pragma unroll
  for (int s = 0; s < 2; ++s){
    gload_lds16(kap + (size_t)s * 64 * QKV_S, &K_lds[s][kd]);
    gload_lds16(vap + s * 64,                 &VT_lds[s][kd]);
  }

  int rs = 0, wsl = 2;
  for (int t = 0; t < 16; ++t){
    const int kt = t << 6;
    if (t < 15) asm volatile("s_waitcnt vmcnt(2)" ::: "memory");
    else        asm volatile("s_waitcnt vmcnt(0)" ::: "memory");
    __builtin_amdgcn_s_barrier();
    __builtin_amdgcn_sched_barrier(0);

    if (t + 2 < 16){
      gload_lds16(kap + (size_t)(t + 2) * 64 * QKV_S, &K_lds[wsl][kd]);
      gload_lds16(vap + (t + 2) * 64,                 &VT_lds[wsl][kd]);
    }
    wsl = (wsl + 1 == 3) ? 0 : wsl + 1;

    const u16* Kc  = K_lds[rs];
    const u16* VTc = VT_lds[rs];
    rs = (rs + 1 == 3) ? 0 : rs + 1;

    f32x4 s[4];
    __builtin_amdgcn_s_setprio(1);
    #pragma unroll
    for (int mi = 0; mi < 4; ++mi){
      f32x4 c = {};
      #pragma unroll
      for (int ss = 0; ss < 2; ++ss){
        int r = mi * 16 + lrow;
        int off = r * 128 + (((ss * 4 + lkg) ^ (r & 7)) * 16);
        bf16x8 kb = *(const bf16x8*)((const char*)Kc + off);
        c = __builtin_amdgcn_mfma_f32_16x16x32_bf16(kb, qa[ss], c, 0, 0, 0);
      }
      s[mi] = c;
    }
    __builtin_amdgcn_s_setprio(0);

    float mt = fmaxf(fmaxf(fmaxf(s[0][0], s[0][1]), fmaxf(s[0][2], s[0][3])),
                     fmaxf(fmaxf(s[1][0], s[1][1]), fmaxf(s[1][2], s[1][3])));
    mt = fmaxf(mt, fmaxf(fmaxf(fmaxf(s[2][0], s[2][1]), fmaxf(s[2][2], s[2][3])),
                         fmaxf(fmaxf(s[3][0], s[3][1]), fmaxf(s[3][2], s[3][3]))));
    mt = fmaxf(mt, __shfl_xor(mt, 16));
    mt = fmaxf(mt, __shfl_xor(mt, 32));
    if (!__all(mt <= mrun + 8.f)){       // defer-max
      float mnew = fmaxf(mrun, mt);
      float fsc = exp2f(mrun - mnew);
      lrun *= fsc;
      #pragma unroll
      for (int nf = 0; nf < 4; ++nf){
        #pragma unroll
        for (int r = 0; r < 4; ++r) o[nf][r] *= fsc;
      }
      mrun = mnew;
    }

    float p[16];
    float ls = 0.f;
    #pragma unroll
    for (int mi = 0; mi < 4; ++mi){
      #pragma unroll
      for (int r = 0; r < 4; ++r){
        int key = kt + mi * 16 + lkg * 4 + r;
        float pv = exp2f(s[mi][r] - mrun);
        ls += pv;                          // denominator over ALL keys
        p[mi * 4 + r] = (key <= qg) ? pv : 0.f;
      }
    }
    ls += __shfl_xor(ls, 16);
    ls += __shfl_xor(ls, 32);
    lrun += ls;

    if (kt <= q0 + w * 16 + 15){
      char* pbase = (char*)&P_lds[w][0];
      const int rx = (lrow & 7) << 4;
      #pragma unroll
      for (int mi = 0; mi < 4; ++mi){
        uint2 pk;
        pk.x = pack2bf(p[mi*4+0], p[mi*4+1]);
        pk.y = pack2bf(p[mi*4+2], p[mi*4+3]);
        *(uint2*)(pbase + (lrow * 128 + ((mi * 32 + lkg * 8) ^ rx))) = pk;
      }
      __builtin_amdgcn_s_setprio(1);
      #pragma unroll
      for (int ss = 0; ss < 2; ++ss){
        bf16x8 pb = *(const bf16x8*)(pbase + (lrow * 128 + ((ss * 64 + lkg * 16) ^ rx)));
        #pragma unroll
        for (int nfd = 0; nfd < 4; ++nfd){
          int d = nfd * 16 + lrow;
          int off = d * 128 + (((ss * 4 + lkg) ^ (d & 7)) * 16);
          bf16x8 vb = *(const bf16x8*)((const char*)VTc + off);
          o[nfd] = __builtin_amdgcn_mfma_f32_16x16x32_bf16(vb, pb, o[nfd], 0, 0, 0);
        }
      }
      __builtin_amdgcn_s_setprio(0);
    }
  }

  float rl = 1.0f / lrun;
  #pragma unroll
  for (int nfd = 0; nfd < 4; ++nfd){
    uint2 ov;
    ov.x = pack2bf(o[nfd][0] * rl, o[nfd][1] * rl);
    ov.y = pack2bf(o[nfd][2] * rl, o[nfd][3] * rl);
    *(uint2*)(out + baseo + (size_t)qg * H_ + nfd * 16 + lkg * 4) = ov;
  }
}

extern "C" void kernel_launch(void* const* d_in, const int* in_sizes, int n_in,
                              void* d_out, int out_size, void* d_ws, size_t ws_size,
                              hipStream_t stream)
{
  (void)in_sizes; (void)n_in; (void)out_size; (void)ws_size;
  const float* x    = (const float*)d_in[0];
  const float* Wq   = (const float*)d_in[1];
  const float* bq   = (const float*)d_in[2];
  const float* Wk   = (const float*)d_in[3];
  const float* bk   = (const float*)d_in[4];
  const float* Wv   = (const float*)d_in[5];
  const float* bv   = (const float*)d_in[6];
  const float* Wo   = (const float*)d_in[7];
  const float* bo   = (const float*)d_in[8];
  const float* ln1w = (const float*)d_in[9];
  const float* ln1b = (const float*)d_in[10];
  const float* ln2w = (const float*)d_in[11];
  const float* ln2b = (const float*)d_in[12];
  const float* Wfc  = (const float*)d_in[13];
  const float* bfc  = (const float*)d_in[14];
  const float* Wpr  = (const float*)d_in[15];
  const float* bpr  = (const float*)d_in[16];

  char* ws = (char*)d_ws;
  u16*  WqkvT = (u16*)(ws + ((size_t) 0 << 20));   //  6MB [3072][1024]
  u16*  WoT   = (u16*)(ws + ((size_t) 6 << 20));   //  2MB
  u16*  WfcT  = (u16*)(ws + ((size_t) 8 << 20));   //  8MB [FF][H]
  u16*  WprT  = (u16*)(ws + ((size_t)16 << 20));   //  8MB [H][FF]
  u16*  h1    = (u16*)(ws + ((size_t)24 << 20));   //  8MB; reused as attnout
  u16*  qkvb  = (u16*)(ws + ((size_t)32 << 20));   // 24MB [M][3072]; dead after attn
  float* x1   = (float*)(ws + ((size_t)32 << 20)); // 16MB (reuses qkvb region)
  u16*  h2    = (u16*)(ws + ((size_t)48 << 20));   //  8MB (reuses qkvb region)
  float* bqkv = (float*)(ws + ((size_t)56 << 20)); // 12KB (dead before mb written)
  float* rtab = (float*)(ws + ((size_t)56 << 20) + (64 << 10)); // 256KB (dead before mb)
  u16*  vtg   = (u16*)(ws + ((size_t)57 << 20));   //  8MB [64 bh][64 d][1024 t] (dead before mb)
  u16*  mb    = (u16*)(ws + ((size_t)56 << 20));   // 32MB (overwrites bqkv/rtab/vtg)
  u16*  attnout = h1;

  dim3 blk(256);
  dim3 gblk(512);

  // weights: transpose + bf16 (QKV concatenated; 4 HxH in one launch)
  trans_qkvo_k<<<dim3(H_/64, H_/64, 4), blk, 0, stream>>>(Wq, Wk, Wv, Wo, WqkvT, WoT);
  transpose_cvt<<<dim3(FF_/64, H_/64),  blk, 0, stream>>>(Wfc, WfcT, H_,  FF_);
  transpose_cvt<<<dim3(H_/64,  FF_/64), blk, 0, stream>>>(Wpr, WprT, FF_, H_);
  prep_small_k<<<dim3((QKV_S + T_*32 + 255)/256), blk, 0, stream>>>(bq, bk, bv, bqkv, rtab);

  // LN1
  ln_kernel<<<dim3(M_), blk, 0, stream>>>(x, ln1w, ln1b, h1);
  // fused QKV projection: [M,3072] — grid 768, RING=3
  gemm_kernel<0,3><<<dim3(QKV_S/128, M_/128), gblk, 0, stream>>>(h1, WqkvT, bqkv, nullptr, qkvb, M_, QKV_S, H_);
  // RoPE on q,k slices (exp2 domain); per-head V transpose
  rope_apply_k<<<dim3((B_*T_*NH_*32)/256), blk, 0, stream>>>(qkvb, rtab);
  vtrans_k<<<dim3(T_/64, B_*NH_), blk, 0, stream>>>(qkvb, vtg);
  // attention — 8 waves, 128 q-rows/block
  attn_kernel<<<dim3(T_/128, B_*NH_), dim3(512), 0, stream>>>(qkvb, vtg, attnout);
  // out projection + residual -> x1 (fp32) — grid 256, deep ring
  gemm_kernel<2,6><<<dim3(H_/128, M_/128), gblk, 0, stream>>>(attnout, WoT, bo, x, x1, M_, H_, H_);
  // LN2
  ln_kernel<<<dim3(M_), blk, 0, stream>>>(x1, ln2w, ln2b, h2);
  // MLP — Wfc grid 1024 RING=3; Wpr grid 256 RING=6
  gemm_kernel<1,3><<<dim3(FF_/128, M_/128), gblk, 0, stream>>>(h2, WfcT, bfc, nullptr, mb, M_, FF_, H_);
  gemm_kernel<2,6><<<dim3(H_/128, M_/128), gblk, 0, stream>>>(mb, WprT, bpr, x1, (float*)d_out, M_, H_, FF_);
}